// Round 13
// baseline (72.953 us; speedup 1.0000x reference)
//
#include <hip/hip_runtime.h>
#include <hip/hip_bf16.h>
#include <stdint.h>

typedef __attribute__((ext_vector_type(8))) short short8;
typedef __attribute__((ext_vector_type(4))) float f32x4;
typedef _Float16 f16;
typedef __attribute__((ext_vector_type(8))) f16 f16x8;
typedef __attribute__((ext_vector_type(2))) f16 f16x2;
typedef uint32_t u32;
typedef uint16_t u16;
typedef uint8_t u8;

#define LOG2E 1.4426950408889634f

// B=4, N=2048, Cin=256, F=64, H=4
// Pipeline (4 kernels) — R12 + colsum 1024-block split + k_out full-chip spread:
//  K1 k_front : proj (x@W per head via MFMA; W transposed block-locally in LDS,
//               XOR-swizzled, b64-vectorized writes) + fused exact-fp32 fdots
//               -> Aarr/Barr/Cexp/Dexp || pack adj bits || zero Dsum; hT in FP16
//  K2 k_colsum: (jt, iseg) = 64 j x 64 i x 16 bh (1024 blocks, 4/CU); atomicAdd Dsum
//  K3 k_pv    : P-pairs in fp16 packed math; CD (x16/D) inline in LDS; 128 i/block;
//               j-split -> bf16 partials
//  K4 k_out   : 512 blocks x 64 thr (1 wave = one 16-row MFMA tile, all CUs busy)
//
// ws layout (bytes):
//  adjw : 0x0000000 u32[2048*64]        512KB packed adjacency bits
//  hT   : 0x0080000 fp16[16][64][2048]    4MB per-(b,h) h transposed [f][n]
//  part : 0x0480000 bf16[2][4][2048][256] 8MB pv partials (2 j-halves)
//  Aarr : 0x1480000 f32[16][2048]       128KB exp(f1)
//  Barr : 0x14A0000 f32                 128KB exp(0.2*f1)
//  Cexp : 0x14C0000 f32                 128KB exp(f2)
//  Dexp : 0x14E0000 f32                 128KB exp(0.2*f2)
//  Dsum : 0x1500000 f32[16][2048]       128KB column sums (atomic)

__device__ __forceinline__ u16 f2bf(float f){
  union{float f; u32 u;} x; x.f = f;
  u32 r = x.u + 0x7FFFu + ((x.u >> 16) & 1u);
  return (u16)(r >> 16);
}
__device__ __forceinline__ u32 pkbf(float a, float b){
  __hip_bfloat162 h = __float22bfloat162_rn(float2{a, b});
  union{ __hip_bfloat162 h; u32 u; } cv; cv.h = h;
  return cv.u;
}
__device__ __forceinline__ u32 pkh(float a, float b){
  f16x2 h; h.x = (f16)a; h.y = (f16)b;
  union{ f16x2 h; u32 u; } cv; cv.h = h;
  return cv.u;
}
__device__ __forceinline__ f16x2 uh2(u32 x){ union{u32 u; f16x2 h;} v; v.u = x; return v.h; }
__device__ __forceinline__ u32 h2u(f16x2 x){ union{f16x2 h; u32 u;} v; v.h = x; return v.u; }

// ---------------- K1: proj(+fdots) || pack || zero Dsum ----------------
__global__ __launch_bounds__(256) void k_front(const float* __restrict__ x,
      const float* __restrict__ W, const float* __restrict__ a1, const float* __restrict__ a2,
      const int* __restrict__ adj,
      u8* __restrict__ adjb, u16* __restrict__ hT,
      float* __restrict__ Aarr, float* __restrict__ Barr,
      float* __restrict__ Cexp, float* __restrict__ Dexp,
      float* __restrict__ Dsum){
  int bid = blockIdx.x, t = threadIdx.x;

  if (bid >= 2560){                   // ---- zero Dsum ----
    Dsum[(bid - 2560)*256 + t] = 0.f;
    return;
  }
  if (bid >= 512){                    // ---- pack: 8 adj elems -> 1 byte ----
    int idx = (bid - 512)*256 + t;
    const int4* ap = (const int4*)(adj + (size_t)idx*8);
    int4 v0 = ap[0], v1 = ap[1];
    u32 byte = (u32)(v0.x > 0)        | ((u32)(v0.y > 0) << 1)
             | ((u32)(v0.z > 0) << 2) | ((u32)(v0.w > 0) << 3)
             | ((u32)(v1.x > 0) << 4) | ((u32)(v1.y > 0) << 5)
             | ((u32)(v1.z > 0) << 6) | ((u32)(v1.w > 0) << 7);
    adjb[idx] = (u8)byte;
    return;
  }
  // ---- proj: h = x @ W[head cb]; vectorized W transpose in LDS, XOR-swizzled ----
  __shared__ u16 WL[64*264];
  int rt = bid & 127, cb = bid >> 7;
  const float* Wh = W + (size_t)cb*16384;     // [256 c][64 f]
  {
    int f0 = (t & 15)*4;
    int cg = t >> 4;
    int s = ((f0 >> 2) & 7) << 3;
    #pragma unroll
    for (int it2 = 0; it2 < 4; it2++){
      int c0 = (cg + it2*16)*4;
      float4 wv0 = *(const float4*)(Wh + (size_t)(c0+0)*64 + f0);
      float4 wv1 = *(const float4*)(Wh + (size_t)(c0+1)*64 + f0);
      float4 wv2 = *(const float4*)(Wh + (size_t)(c0+2)*64 + f0);
      float4 wv3 = *(const float4*)(Wh + (size_t)(c0+3)*64 + f0);
      int cc = c0 ^ s;
      #pragma unroll
      for (int k = 0; k < 4; k++){
        u32 lo = pkbf((&wv0.x)[k], (&wv1.x)[k]);
        u32 hi = pkbf((&wv2.x)[k], (&wv3.x)[k]);
        *(uint2*)&WL[(f0+k)*264 + cc] = uint2{lo, hi};
      }
    }
  }
  __syncthreads();

  int w = t >> 6, l = t & 63;
  int rA = rt*64 + w*16 + (l & 15);
  int kg = (l >> 4) * 8;
  int rowq[4], rswq[4];
  #pragma unroll
  for (int q = 0; q < 4; q++){
    rowq[q] = q*16 + (l & 15);
    rswq[q] = ((rowq[q] >> 2) & 7) << 3;
  }
  f32x4 acc[4] = {};
  const float* xrow = x + (size_t)rA * 256;
  #pragma unroll
  for (int ks = 0; ks < 8; ks++){
    int c = ks*32 + kg;
    float4 xa = *(const float4*)(xrow + c);
    float4 xb = *(const float4*)(xrow + c + 4);
    union{u32 w[4]; short8 v;} A;
    A.w[0] = pkbf(xa.x, xa.y); A.w[1] = pkbf(xa.z, xa.w);
    A.w[2] = pkbf(xb.x, xb.y); A.w[3] = pkbf(xb.z, xb.w);
    #pragma unroll
    for (int q = 0; q < 4; q++){
      short8 Bf = *(const short8*)&WL[rowq[q]*264 + (c ^ rswq[q])];
      acc[q] = __builtin_amdgcn_mfma_f32_16x16x32_bf16(A.v, Bf, acc[q], 0, 0, 0);
    }
  }
  int rb = rt*64 + w*16 + (l >> 4)*4;
  int b = rb >> 11, n = rb & 2047;
  #pragma unroll
  for (int q = 0; q < 4; q++){
    int f = q*16 + (l & 15);
    u32 p0 = pkh(acc[q][0], acc[q][1]);
    u32 p1 = pkh(acc[q][2], acc[q][3]);
    u16* dst = hT + ((size_t)(b*4 + cb)*64 + f)*2048 + n;
    *(uint2*)dst = uint2{p0, p1};
  }
  float a1v[4], a2v[4];
  #pragma unroll
  for (int q = 0; q < 4; q++){
    a1v[q] = a1[cb*64 + q*16 + (l & 15)];
    a2v[q] = a2[cb*64 + q*16 + (l & 15)];
  }
  float s1[4], s2[4];
  #pragma unroll
  for (int r = 0; r < 4; r++){
    s1[r] = acc[0][r]*a1v[0] + acc[1][r]*a1v[1] + acc[2][r]*a1v[2] + acc[3][r]*a1v[3];
    s2[r] = acc[0][r]*a2v[0] + acc[1][r]*a2v[1] + acc[2][r]*a2v[2] + acc[3][r]*a2v[3];
  }
  #pragma unroll
  for (int m = 1; m <= 8; m <<= 1){
    #pragma unroll
    for (int r = 0; r < 4; r++){
      s1[r] += __shfl_xor(s1[r], m);
      s2[r] += __shfl_xor(s2[r], m);
    }
  }
  if ((l & 15) == 0){
    #pragma unroll
    for (int r = 0; r < 4; r++){
      int row = rb + r;
      int bb = row >> 11, nn = row & 2047;
      int o = (bb*4 + cb)*2048 + nn;
      float fa = s1[r] * LOG2E;
      Aarr[o] = __builtin_amdgcn_exp2f(fa);
      Barr[o] = __builtin_amdgcn_exp2f(0.2f*fa);
      float fb = s2[r] * LOG2E;
      Cexp[o] = __builtin_amdgcn_exp2f(fb);
      Dexp[o] = __builtin_amdgcn_exp2f(0.2f*fb);
    }
  }
}

// ---------------- K2: colsum (64 j x 64 i x 16 bh, 1024 blocks) -> atomic Dsum ----------------
__global__ __launch_bounds__(256) void k_colsum(const u32* __restrict__ adjw,
      const float* __restrict__ Aarr, const float* __restrict__ Barr,
      const float* __restrict__ Cexp, const float* __restrict__ Dexp,
      float* __restrict__ Dsum){
  __shared__ float AL[64*16], BL[64*16];     // [i][bh] f32, 8KB
  __shared__ float red[4][1024];             // [wave][bh*64+j] 16KB
  int jt = blockIdx.x;      // 32 j-tiles of 64
  int is = blockIdx.y;      // 32 i-segments of 64
  int t = threadIdx.x, w = t >> 6, l = t & 63;
  int i0 = is*64;
  for (int k = t; k < 1024; k += 256){
    int bh = k >> 6, ii = k & 63;
    AL[ii*16 + bh] = Aarr[bh*2048 + i0 + ii];
    BL[ii*16 + bh] = Barr[bh*2048 + i0 + ii];
  }
  int j = jt*64 + l;
  float Cj[16], Dj[16];
  #pragma unroll
  for (int bh = 0; bh < 16; bh++){
    Cj[bh] = Cexp[bh*2048 + j];
    Dj[bh] = Dexp[bh*2048 + j];
  }
  float acc[16] = {};
  __syncthreads();
  int wi = jt*2 + (l >> 5), sh = l & 31;
  const u32* aw = adjw + wi;
  #pragma unroll 2
  for (int ii = w*16; ii < w*16 + 16; ii++){
    u32 m = aw[(size_t)(i0 + ii)*64];
    float bitf = (float)((m >> sh) & 1u);
    const float* ar = &AL[ii*16];
    const float* br = &BL[ii*16];
    #pragma unroll
    for (int q = 0; q < 4; q++){
      float4 a4 = *(const float4*)(ar + q*4);
      float4 b4 = *(const float4*)(br + q*4);
      acc[q*4+0] = fmaf(fmaxf(a4.x*Cj[q*4+0], b4.x*Dj[q*4+0]), bitf, acc[q*4+0]);
      acc[q*4+1] = fmaf(fmaxf(a4.y*Cj[q*4+1], b4.y*Dj[q*4+1]), bitf, acc[q*4+1]);
      acc[q*4+2] = fmaf(fmaxf(a4.z*Cj[q*4+2], b4.z*Dj[q*4+2]), bitf, acc[q*4+2]);
      acc[q*4+3] = fmaf(fmaxf(a4.w*Cj[q*4+3], b4.w*Dj[q*4+3]), bitf, acc[q*4+3]);
    }
  }
  #pragma unroll
  for (int bh = 0; bh < 16; bh++) red[w][bh*64 + l] = acc[bh];
  __syncthreads();
  #pragma unroll
  for (int k = 0; k < 4; k++){
    int e = t*4 + k;
    float s = (red[0][e] + red[1][e]) + (red[2][e] + red[3][e]);
    int bh = e >> 6, jl = e & 63;
    atomicAdd(&Dsum[bh*2048 + jt*64 + jl], s);
  }
}

// ---------------- K3: fused PV, fp16 packed P; bf16 partials ----------------
__global__ __launch_bounds__(256) void k_pv(const u32* __restrict__ adjw, const u16* __restrict__ hT,
      const float* __restrict__ Aarr, const float* __restrict__ Barr,
      const float* __restrict__ Cexp, const float* __restrict__ Dexp,
      const float* __restrict__ Dsum, u16* __restrict__ part){
  int it = blockIdx.x;           // 16 i-tiles of 128
  int bh = blockIdx.y;           // 16
  int jh = blockIdx.z;           // 2 j-halves
  int b = bh >> 2, h = bh & 3;
  int t = threadIdx.x;
  int w = t >> 6, l = t & 63;

  __shared__ u16 hTl[64*136];    // 17.4KB fp16 [f][j] stride 136
  __shared__ u32 CA2l[512];      // fp16x2 pairs: Ca*16/D for (2j,2j+1)
  __shared__ u32 DB2l[512];

  {  // inline CD (scaled x16): 4 j per thread
    int gj = bh*2048 + jh*1024 + t*4;
    float4 c4 = *(const float4*)(Cexp + gj);
    float4 d4 = *(const float4*)(Dexp + gj);
    float4 s4 = *(const float4*)(Dsum + gj);
    float i0v = 16.0f/s4.x, i1v = 16.0f/s4.y, i2v = 16.0f/s4.z, i3v = 16.0f/s4.w;
    CA2l[t*2]   = pkh(c4.x*i0v, c4.y*i1v);
    CA2l[t*2+1] = pkh(c4.z*i2v, c4.w*i3v);
    DB2l[t*2]   = pkh(d4.x*i0v, d4.y*i1v);
    DB2l[t*2+1] = pkh(d4.z*i2v, d4.w*i3v);
  }

  int i0 = it*128 + w*32 + (l & 15);  // row-block 0; row-block 1 = i0+16
  f16x2 Ai02, Bi02, Ai12, Bi12;
  {
    const float sc = 0.0625f;   // 1/16
    float A0 = Aarr[bh*2048 + i0] * sc,      B0 = Barr[bh*2048 + i0] * sc;
    float A1 = Aarr[bh*2048 + i0 + 16] * sc, B1 = Barr[bh*2048 + i0 + 16] * sc;
    Ai02 = uh2(pkh(A0, A0)); Bi02 = uh2(pkh(B0, B0));
    Ai12 = uh2(pkh(A1, A1)); Bi12 = uh2(pkh(B1, B1));
  }
  const u16* hTr = hT + (size_t)bh * 64 * 2048;
  int kg = (l >> 4) * 8;
  f32x4 acc[2][4] = {};

  for (int jj = 0; jj < 1024; jj += 128){
    int jc = jh*1024 + jj;
    __syncthreads();
    {  // stage hT tile [64 f][128 j]
      int f = t >> 2, seg = (t & 3) * 32;
      const u16* src = hTr + (size_t)f*2048 + jc + seg;
      u16* d = hTl + f*136 + seg;
      *(uint4*)(d)      = *(const uint4*)(src);
      *(uint4*)(d + 8)  = *(const uint4*)(src + 8);
      *(uint4*)(d + 16) = *(const uint4*)(src + 16);
      *(uint4*)(d + 24) = *(const uint4*)(src + 24);
    }
    __syncthreads();
    uint4 mw0 = *(const uint4*)(adjw + (size_t)i0*64 + (jc >> 5));
    uint4 mw1 = *(const uint4*)(adjw + (size_t)(i0+16)*64 + (jc >> 5));
    #pragma unroll
    for (int ks = 0; ks < 4; ks++){
      int pbase = (jj >> 1) + ks*16 + (l >> 4)*4;
      uint4 ca2 = *(const uint4*)&CA2l[pbase];
      uint4 db2 = *(const uint4*)&DB2l[pbase];
      u32 w0 = (&mw0.x)[ks] >> kg;
      u32 w1 = (&mw1.x)[ks] >> kg;
      union{u32 w[4]; f16x8 v;} A0u, A1u;
      #pragma unroll
      for (int p = 0; p < 4; p++){
        f16x2 cav = uh2((&ca2.x)[p]);
        f16x2 dbv = uh2((&db2.x)[p]);
        f16x2 e0 = __builtin_elementwise_max(Ai02*cav, Bi02*dbv);
        f16x2 e1 = __builtin_elementwise_max(Ai12*cav, Bi12*dbv);
        u32 m0 = ((u32)((int)(w0 << (31-2*p)) >> 31) & 0x0000FFFFu)
               | ((u32)((int)(w0 << (30-2*p)) >> 31) & 0xFFFF0000u);
        u32 m1 = ((u32)((int)(w1 << (31-2*p)) >> 31) & 0x0000FFFFu)
               | ((u32)((int)(w1 << (30-2*p)) >> 31) & 0xFFFF0000u);
        A0u.w[p] = h2u(e0) & m0;
        A1u.w[p] = h2u(e1) & m1;
      }
      #pragma unroll
      for (int q = 0; q < 4; q++){
        f16x8 Bf = *(const f16x8*)&hTl[(q*16 + (l & 15))*136 + ks*32 + kg];
        acc[0][q] = __builtin_amdgcn_mfma_f32_16x16x32_f16(A0u.v, Bf, acc[0][q], 0, 0, 0);
        acc[1][q] = __builtin_amdgcn_mfma_f32_16x16x32_f16(A1u.v, Bf, acc[1][q], 0, 0, 0);
      }
    }
  }
  // epilogue: write bf16 partial [jh][b][n][h*64+f]
  u16* pr = part + ((size_t)(jh*4 + b)*2048)*256;
  #pragma unroll
  for (int r = 0; r < 2; r++){
    int nb = it*128 + w*32 + r*16 + (l >> 4)*4;
    #pragma unroll
    for (int q = 0; q < 4; q++){
      int f = h*64 + q*16 + (l & 15);
      #pragma unroll
      for (int rr = 0; rr < 4; rr++){
        pr[(size_t)(nb + rr)*256 + f] = f2bf(acc[r][q][rr]);
      }
    }
  }
}

// ---------------- K4: out (1 wave/block, 512 blocks) ----------------
__global__ __launch_bounds__(64) void k_out(const u16* __restrict__ part,
                       const float* __restrict__ Wl, const float* __restrict__ bl,
                       float* __restrict__ out){
  int rt = blockIdx.x;              // 512 tiles of 16 rows
  int l = threadIdx.x & 63;
  int rA = rt*16 + (l & 15);
  int b = rA >> 11, n = rA & 2047;
  const u16* p0 = part + ((size_t)b*2048 + n)*256;
  const u16* p1 = part + ((size_t)(4 + b)*2048 + n)*256;
  int kg = (l >> 4) * 8;
  f32x4 acc[4] = {};
  #pragma unroll
  for (int ks = 0; ks < 8; ks++){
    int c = ks*32 + kg;
    short8 v0 = *(const short8*)(p0 + c);
    short8 v1 = *(const short8*)(p1 + c);
    float av[8];
    #pragma unroll
    for (int e = 0; e < 8; e++){
      union{u32 u; float f;} x0, x1;
      x0.u = ((u32)(u16)v0[e]) << 16;
      x1.u = ((u32)(u16)v1[e]) << 16;
      av[e] = fmaxf(x0.f + x1.f, 0.f);
    }
    union{u32 w[4]; short8 v;} A;
    A.w[0] = pkbf(av[0], av[1]); A.w[1] = pkbf(av[2], av[3]);
    A.w[2] = pkbf(av[4], av[5]); A.w[3] = pkbf(av[6], av[7]);
    #pragma unroll
    for (int q = 0; q < 4; q++){
      const float* wr = Wl + (size_t)(q*16 + (l & 15))*256 + c;
      float4 u0 = *(const float4*)(wr);
      float4 u1 = *(const float4*)(wr + 4);
      union{u32 w[4]; short8 v;} Bv;
      Bv.w[0] = pkbf(u0.x, u0.y); Bv.w[1] = pkbf(u0.z, u0.w);
      Bv.w[2] = pkbf(u1.x, u1.y); Bv.w[3] = pkbf(u1.z, u1.w);
      acc[q] = __builtin_amdgcn_mfma_f32_16x16x32_bf16(A.v, Bv.v, acc[q], 0, 0, 0);
    }
  }
  int rb = rt*16 + (l >> 4)*4;
  #pragma unroll
  for (int q = 0; q < 4; q++){
    int o = q*16 + (l & 15);
    float bv = bl[o];
    #pragma unroll
    for (int r = 0; r < 4; r++){
      float v = acc[q][r] + bv;
      out[(size_t)(rb + r)*64 + o] = fmaxf(v, 0.2f*v);
    }
  }
}

extern "C" void kernel_launch(void* const* d_in, const int* in_sizes, int n_in,
                              void* d_out, int out_size, void* d_ws, size_t ws_size,
                              hipStream_t stream) {
  const float* x  = (const float*)d_in[0];
  const int* adj  = (const int*)d_in[1];
  const float* W  = (const float*)d_in[2];
  const float* a1 = (const float*)d_in[3];
  const float* a2 = (const float*)d_in[4];
  const float* Wl = (const float*)d_in[5];
  const float* bl = (const float*)d_in[6];
  float* out = (float*)d_out;
  char* ws = (char*)d_ws;

  u32* adjw    = (u32*)(ws + 0x0000000);
  u16* hT      = (u16*)(ws + 0x0080000);
  u16* part    = (u16*)(ws + 0x0480000);
  float* Aarr  = (float*)(ws + 0x1480000);
  float* Barr  = (float*)(ws + 0x14A0000);
  float* Cexp  = (float*)(ws + 0x14C0000);
  float* Dexp  = (float*)(ws + 0x14E0000);
  float* Dsum  = (float*)(ws + 0x1500000);

  k_front<<<2688, 256, 0, stream>>>(x, W, a1, a2, adj, (u8*)adjw, hT, Aarr, Barr, Cexp, Dexp, Dsum);
  k_colsum<<<dim3(32, 32), 256, 0, stream>>>(adjw, Aarr, Barr, Cexp, Dexp, Dsum);
  k_pv<<<dim3(16, 16, 2), 256, 0, stream>>>(adjw, hT, Aarr, Barr, Cexp, Dexp, Dsum, part);
  k_out<<<512, 64, 0, stream>>>(part, Wl, bl, out);
}

// Round 14
// 72.689 us; speedup vs baseline: 1.0036x; 1.0036x over previous
//
#include <hip/hip_runtime.h>
#include <hip/hip_bf16.h>
#include <stdint.h>

typedef __attribute__((ext_vector_type(8))) short short8;
typedef __attribute__((ext_vector_type(4))) float f32x4;
typedef _Float16 f16;
typedef __attribute__((ext_vector_type(8))) f16 f16x8;
typedef __attribute__((ext_vector_type(2))) f16 f16x2;
typedef uint32_t u32;
typedef uint16_t u16;
typedef uint8_t u8;

#define LOG2E 1.4426950408889634f

// B=4, N=2048, Cin=256, F=64, H=4
// Pipeline (4 kernels) — R12 baseline + pv full-j producing final cat:
//  K1 k_front : proj (x@W per head via MFMA; W transposed block-locally in LDS,
//               XOR-swizzled, b64-vectorized writes) + fused exact-fp32 fdots
//               -> Aarr/Barr/Cexp/Dexp || pack adj bits || zero Dsum; hT in FP16
//  K2 k_colsum: (jt, iseg) = 64 j x 128 i x 16 bh (R12-proven); atomicAdd Dsum
//  K3 k_pv    : FULL-j sweep per block (16x16 grid, 512 thr, 8 waves, 16 i/wave);
//               fp16 packed P; CD (x16/D) inline in LDS; relu in epilogue ->
//               final cat bf16 (no partials)
//  K4 k_out   : out = leaky(cat @ Wl^T + bl); cat IS the A-frag (no cvt work)
//
// ws layout (bytes):
//  adjw : 0x0000000 u32[2048*64]        512KB packed adjacency bits
//  hT   : 0x0080000 fp16[16][64][2048]    4MB per-(b,h) h transposed [f][n]
//  cat  : 0x0480000 bf16[4][2048][256]    4MB relu(hp) concat heads
//  Aarr : 0x1480000 f32[16][2048]       128KB exp(f1)
//  Barr : 0x14A0000 f32                 128KB exp(0.2*f1)
//  Cexp : 0x14C0000 f32                 128KB exp(f2)
//  Dexp : 0x14E0000 f32                 128KB exp(0.2*f2)
//  Dsum : 0x1500000 f32[16][2048]       128KB column sums (atomic)

__device__ __forceinline__ u16 f2bf(float f){
  union{float f; u32 u;} x; x.f = f;
  u32 r = x.u + 0x7FFFu + ((x.u >> 16) & 1u);
  return (u16)(r >> 16);
}
__device__ __forceinline__ u32 pkbf(float a, float b){
  __hip_bfloat162 h = __float22bfloat162_rn(float2{a, b});
  union{ __hip_bfloat162 h; u32 u; } cv; cv.h = h;
  return cv.u;
}
__device__ __forceinline__ u32 pkh(float a, float b){
  f16x2 h; h.x = (f16)a; h.y = (f16)b;
  union{ f16x2 h; u32 u; } cv; cv.h = h;
  return cv.u;
}
__device__ __forceinline__ f16x2 uh2(u32 x){ union{u32 u; f16x2 h;} v; v.u = x; return v.h; }
__device__ __forceinline__ u32 h2u(f16x2 x){ union{f16x2 h; u32 u;} v; v.h = x; return v.u; }

// ---------------- K1: proj(+fdots) || pack || zero Dsum ----------------
__global__ __launch_bounds__(256) void k_front(const float* __restrict__ x,
      const float* __restrict__ W, const float* __restrict__ a1, const float* __restrict__ a2,
      const int* __restrict__ adj,
      u8* __restrict__ adjb, u16* __restrict__ hT,
      float* __restrict__ Aarr, float* __restrict__ Barr,
      float* __restrict__ Cexp, float* __restrict__ Dexp,
      float* __restrict__ Dsum){
  int bid = blockIdx.x, t = threadIdx.x;

  if (bid >= 2560){                   // ---- zero Dsum ----
    Dsum[(bid - 2560)*256 + t] = 0.f;
    return;
  }
  if (bid >= 512){                    // ---- pack: 8 adj elems -> 1 byte ----
    int idx = (bid - 512)*256 + t;
    const int4* ap = (const int4*)(adj + (size_t)idx*8);
    int4 v0 = ap[0], v1 = ap[1];
    u32 byte = (u32)(v0.x > 0)        | ((u32)(v0.y > 0) << 1)
             | ((u32)(v0.z > 0) << 2) | ((u32)(v0.w > 0) << 3)
             | ((u32)(v1.x > 0) << 4) | ((u32)(v1.y > 0) << 5)
             | ((u32)(v1.z > 0) << 6) | ((u32)(v1.w > 0) << 7);
    adjb[idx] = (u8)byte;
    return;
  }
  // ---- proj: h = x @ W[head cb]; vectorized W transpose in LDS, XOR-swizzled ----
  __shared__ u16 WL[64*264];
  int rt = bid & 127, cb = bid >> 7;
  const float* Wh = W + (size_t)cb*16384;     // [256 c][64 f]
  {
    int f0 = (t & 15)*4;
    int cg = t >> 4;
    int s = ((f0 >> 2) & 7) << 3;
    #pragma unroll
    for (int it2 = 0; it2 < 4; it2++){
      int c0 = (cg + it2*16)*4;
      float4 wv0 = *(const float4*)(Wh + (size_t)(c0+0)*64 + f0);
      float4 wv1 = *(const float4*)(Wh + (size_t)(c0+1)*64 + f0);
      float4 wv2 = *(const float4*)(Wh + (size_t)(c0+2)*64 + f0);
      float4 wv3 = *(const float4*)(Wh + (size_t)(c0+3)*64 + f0);
      int cc = c0 ^ s;
      #pragma unroll
      for (int k = 0; k < 4; k++){
        u32 lo = pkbf((&wv0.x)[k], (&wv1.x)[k]);
        u32 hi = pkbf((&wv2.x)[k], (&wv3.x)[k]);
        *(uint2*)&WL[(f0+k)*264 + cc] = uint2{lo, hi};
      }
    }
  }
  __syncthreads();

  int w = t >> 6, l = t & 63;
  int rA = rt*64 + w*16 + (l & 15);
  int kg = (l >> 4) * 8;
  int rowq[4], rswq[4];
  #pragma unroll
  for (int q = 0; q < 4; q++){
    rowq[q] = q*16 + (l & 15);
    rswq[q] = ((rowq[q] >> 2) & 7) << 3;
  }
  f32x4 acc[4] = {};
  const float* xrow = x + (size_t)rA * 256;
  #pragma unroll
  for (int ks = 0; ks < 8; ks++){
    int c = ks*32 + kg;
    float4 xa = *(const float4*)(xrow + c);
    float4 xb = *(const float4*)(xrow + c + 4);
    union{u32 w[4]; short8 v;} A;
    A.w[0] = pkbf(xa.x, xa.y); A.w[1] = pkbf(xa.z, xa.w);
    A.w[2] = pkbf(xb.x, xb.y); A.w[3] = pkbf(xb.z, xb.w);
    #pragma unroll
    for (int q = 0; q < 4; q++){
      short8 Bf = *(const short8*)&WL[rowq[q]*264 + (c ^ rswq[q])];
      acc[q] = __builtin_amdgcn_mfma_f32_16x16x32_bf16(A.v, Bf, acc[q], 0, 0, 0);
    }
  }
  int rb = rt*64 + w*16 + (l >> 4)*4;
  int b = rb >> 11, n = rb & 2047;
  #pragma unroll
  for (int q = 0; q < 4; q++){
    int f = q*16 + (l & 15);
    u32 p0 = pkh(acc[q][0], acc[q][1]);
    u32 p1 = pkh(acc[q][2], acc[q][3]);
    u16* dst = hT + ((size_t)(b*4 + cb)*64 + f)*2048 + n;
    *(uint2*)dst = uint2{p0, p1};
  }
  float a1v[4], a2v[4];
  #pragma unroll
  for (int q = 0; q < 4; q++){
    a1v[q] = a1[cb*64 + q*16 + (l & 15)];
    a2v[q] = a2[cb*64 + q*16 + (l & 15)];
  }
  float s1[4], s2[4];
  #pragma unroll
  for (int r = 0; r < 4; r++){
    s1[r] = acc[0][r]*a1v[0] + acc[1][r]*a1v[1] + acc[2][r]*a1v[2] + acc[3][r]*a1v[3];
    s2[r] = acc[0][r]*a2v[0] + acc[1][r]*a2v[1] + acc[2][r]*a2v[2] + acc[3][r]*a2v[3];
  }
  #pragma unroll
  for (int m = 1; m <= 8; m <<= 1){
    #pragma unroll
    for (int r = 0; r < 4; r++){
      s1[r] += __shfl_xor(s1[r], m);
      s2[r] += __shfl_xor(s2[r], m);
    }
  }
  if ((l & 15) == 0){
    #pragma unroll
    for (int r = 0; r < 4; r++){
      int row = rb + r;
      int bb = row >> 11, nn = row & 2047;
      int o = (bb*4 + cb)*2048 + nn;
      float fa = s1[r] * LOG2E;
      Aarr[o] = __builtin_amdgcn_exp2f(fa);
      Barr[o] = __builtin_amdgcn_exp2f(0.2f*fa);
      float fb = s2[r] * LOG2E;
      Cexp[o] = __builtin_amdgcn_exp2f(fb);
      Dexp[o] = __builtin_amdgcn_exp2f(0.2f*fb);
    }
  }
}

// ---------------- K2: colsum (R12-proven form) -> atomic Dsum ----------------
__global__ __launch_bounds__(256) void k_colsum(const u32* __restrict__ adjw,
      const float* __restrict__ Aarr, const float* __restrict__ Barr,
      const float* __restrict__ Cexp, const float* __restrict__ Dexp,
      float* __restrict__ Dsum){
  __shared__ float AL[128*16], BL[128*16];
  __shared__ float red[4][1024];
  int jt = blockIdx.x;      // 32 j-tiles of 64
  int is = blockIdx.y;      // 16 i-segments of 128
  int t = threadIdx.x, w = t >> 6, l = t & 63;
  int i0 = is*128;
  for (int k = t; k < 2048; k += 256){
    int bh = k >> 7, ii = k & 127;
    AL[ii*16 + bh] = Aarr[bh*2048 + i0 + ii];
    BL[ii*16 + bh] = Barr[bh*2048 + i0 + ii];
  }
  int j = jt*64 + l;
  float Cj[16], Dj[16];
  #pragma unroll
  for (int bh = 0; bh < 16; bh++){
    Cj[bh] = Cexp[bh*2048 + j];
    Dj[bh] = Dexp[bh*2048 + j];
  }
  float acc[16] = {};
  __syncthreads();
  int wi = jt*2 + (l >> 5), sh = l & 31;
  const u32* aw = adjw + wi;
  #pragma unroll 2
  for (int ii = w*32; ii < w*32 + 32; ii++){
    u32 m = aw[(size_t)(i0 + ii)*64];
    float bitf = (float)((m >> sh) & 1u);
    const float* ar = &AL[ii*16];
    const float* br = &BL[ii*16];
    #pragma unroll
    for (int q = 0; q < 4; q++){
      float4 a4 = *(const float4*)(ar + q*4);
      float4 b4 = *(const float4*)(br + q*4);
      acc[q*4+0] = fmaf(fmaxf(a4.x*Cj[q*4+0], b4.x*Dj[q*4+0]), bitf, acc[q*4+0]);
      acc[q*4+1] = fmaf(fmaxf(a4.y*Cj[q*4+1], b4.y*Dj[q*4+1]), bitf, acc[q*4+1]);
      acc[q*4+2] = fmaf(fmaxf(a4.z*Cj[q*4+2], b4.z*Dj[q*4+2]), bitf, acc[q*4+2]);
      acc[q*4+3] = fmaf(fmaxf(a4.w*Cj[q*4+3], b4.w*Dj[q*4+3]), bitf, acc[q*4+3]);
    }
  }
  #pragma unroll
  for (int bh = 0; bh < 16; bh++) red[w][bh*64 + l] = acc[bh];
  __syncthreads();
  #pragma unroll
  for (int k = 0; k < 4; k++){
    int e = t*4 + k;
    float s = (red[0][e] + red[1][e]) + (red[2][e] + red[3][e]);
    int bh = e >> 6, jl = e & 63;
    atomicAdd(&Dsum[bh*2048 + jt*64 + jl], s);
  }
}

// ---------------- K3: fused PV, full-j, fp16 packed P; relu -> cat bf16 ----------------
__global__ __launch_bounds__(512) void k_pv(const u32* __restrict__ adjw, const u16* __restrict__ hT,
      const float* __restrict__ Aarr, const float* __restrict__ Barr,
      const float* __restrict__ Cexp, const float* __restrict__ Dexp,
      const float* __restrict__ Dsum, u16* __restrict__ cat){
  int it = blockIdx.x;           // 16 i-tiles of 128
  int bh = blockIdx.y;           // 16
  int b = bh >> 2, h = bh & 3;
  int t = threadIdx.x;           // 512 threads, 8 waves
  int w = t >> 6, l = t & 63;

  __shared__ u16 hTl[64*136];    // 17.4KB fp16 [f][j] stride 136
  __shared__ u32 CA2l[1024];     // fp16x2 pairs: Ca*16/D for (2j,2j+1), full j
  __shared__ u32 DB2l[1024];

  {  // inline CD (scaled x16): 4 j per thread over full 2048 j
    int gj = bh*2048 + t*4;
    float4 c4 = *(const float4*)(Cexp + gj);
    float4 d4 = *(const float4*)(Dexp + gj);
    float4 s4 = *(const float4*)(Dsum + gj);
    float i0v = 16.0f/s4.x, i1v = 16.0f/s4.y, i2v = 16.0f/s4.z, i3v = 16.0f/s4.w;
    CA2l[t*2]   = pkh(c4.x*i0v, c4.y*i1v);
    CA2l[t*2+1] = pkh(c4.z*i2v, c4.w*i3v);
    DB2l[t*2]   = pkh(d4.x*i0v, d4.y*i1v);
    DB2l[t*2+1] = pkh(d4.z*i2v, d4.w*i3v);
  }

  int i0 = it*128 + w*16 + (l & 15);   // 8 waves x 16 i = 128 i per block
  f16x2 Ai2, Bi2;
  {
    const float sc = 0.0625f;   // 1/16
    float A0 = Aarr[bh*2048 + i0] * sc, B0 = Barr[bh*2048 + i0] * sc;
    Ai2 = uh2(pkh(A0, A0)); Bi2 = uh2(pkh(B0, B0));
  }
  const u16* hTr = hT + (size_t)bh * 64 * 2048;
  int kg = (l >> 4) * 8;
  f32x4 acc[4] = {};

  for (int jc = 0; jc < 2048; jc += 128){
    __syncthreads();
    {  // stage hT tile [64 f][128 j]: 512 threads x 32B
      int f = t >> 3, seg = (t & 7) * 16;
      const u16* src = hTr + (size_t)f*2048 + jc + seg;
      u16* d = hTl + f*136 + seg;
      *(uint4*)(d)     = *(const uint4*)(src);
      *(uint4*)(d + 8) = *(const uint4*)(src + 8);
    }
    __syncthreads();
    uint4 mw = *(const uint4*)(adjw + (size_t)i0*64 + (jc >> 5));
    #pragma unroll
    for (int ks = 0; ks < 4; ks++){
      int pbase = (jc >> 1) + ks*16 + (l >> 4)*4;
      uint4 ca2 = *(const uint4*)&CA2l[pbase];
      uint4 db2 = *(const uint4*)&DB2l[pbase];
      u32 w0 = (&mw.x)[ks] >> kg;
      union{u32 w[4]; f16x8 v;} A0u;
      #pragma unroll
      for (int p = 0; p < 4; p++){
        f16x2 cav = uh2((&ca2.x)[p]);
        f16x2 dbv = uh2((&db2.x)[p]);
        f16x2 e0 = __builtin_elementwise_max(Ai2*cav, Bi2*dbv);
        u32 m0 = ((u32)((int)(w0 << (31-2*p)) >> 31) & 0x0000FFFFu)
               | ((u32)((int)(w0 << (30-2*p)) >> 31) & 0xFFFF0000u);
        A0u.w[p] = h2u(e0) & m0;
      }
      #pragma unroll
      for (int q = 0; q < 4; q++){
        f16x8 Bf = *(const f16x8*)&hTl[(q*16 + (l & 15))*136 + ks*32 + kg];
        acc[q] = __builtin_amdgcn_mfma_f32_16x16x32_f16(A0u.v, Bf, acc[q], 0, 0, 0);
      }
    }
  }
  // epilogue: relu + bf16, final cat[b][n][h*64+f]
  int nb = it*128 + w*16 + (l >> 4)*4;
  #pragma unroll
  for (int q = 0; q < 4; q++){
    int f = h*64 + q*16 + (l & 15);
    #pragma unroll
    for (int rr = 0; rr < 4; rr++){
      cat[((size_t)(b*2048 + nb + rr))*256 + f] = f2bf(fmaxf(acc[q][rr], 0.f));
    }
  }
}

// ---------------- K4: out = leaky(cat @ Wl^T + bl); cat bf16 is the A-frag ----------------
__global__ __launch_bounds__(256) void k_out(const u16* __restrict__ cat,
                       const float* __restrict__ Wl, const float* __restrict__ bl,
                       float* __restrict__ out){
  int rt = blockIdx.x;
  int w = threadIdx.x >> 6, l = threadIdx.x & 63;
  int rA = rt*64 + w*16 + (l & 15);
  int kg = (l >> 4) * 8;
  f32x4 acc[4] = {};
  #pragma unroll
  for (int ks = 0; ks < 8; ks++){
    int c = ks*32 + kg;
    short8 Af = *(const short8*)(cat + (size_t)rA*256 + c);
    #pragma unroll
    for (int q = 0; q < 4; q++){
      const float* wr = Wl + (size_t)(q*16 + (l & 15))*256 + c;
      float4 u0 = *(const float4*)(wr);
      float4 u1 = *(const float4*)(wr + 4);
      union{u32 w[4]; short8 v;} Bv;
      Bv.w[0] = pkbf(u0.x, u0.y); Bv.w[1] = pkbf(u0.z, u0.w);
      Bv.w[2] = pkbf(u1.x, u1.y); Bv.w[3] = pkbf(u1.z, u1.w);
      acc[q] = __builtin_amdgcn_mfma_f32_16x16x32_bf16(Af, Bv.v, acc[q], 0, 0, 0);
    }
  }
  int rb = rt*64 + w*16 + (l >> 4)*4;
  #pragma unroll
  for (int q = 0; q < 4; q++){
    int o = q*16 + (l & 15);
    float bv = bl[o];
    #pragma unroll
    for (int r = 0; r < 4; r++){
      float v = acc[q][r] + bv;
      out[(size_t)(rb + r)*64 + o] = fmaxf(v, 0.2f*v);
    }
  }
}

extern "C" void kernel_launch(void* const* d_in, const int* in_sizes, int n_in,
                              void* d_out, int out_size, void* d_ws, size_t ws_size,
                              hipStream_t stream) {
  const float* x  = (const float*)d_in[0];
  const int* adj  = (const int*)d_in[1];
  const float* W  = (const float*)d_in[2];
  const float* a1 = (const float*)d_in[3];
  const float* a2 = (const float*)d_in[4];
  const float* Wl = (const float*)d_in[5];
  const float* bl = (const float*)d_in[6];
  float* out = (float*)d_out;
  char* ws = (char*)d_ws;

  u32* adjw    = (u32*)(ws + 0x0000000);
  u16* hT      = (u16*)(ws + 0x0080000);
  u16* cat     = (u16*)(ws + 0x0480000);
  float* Aarr  = (float*)(ws + 0x1480000);
  float* Barr  = (float*)(ws + 0x14A0000);
  float* Cexp  = (float*)(ws + 0x14C0000);
  float* Dexp  = (float*)(ws + 0x14E0000);
  float* Dsum  = (float*)(ws + 0x1500000);

  k_front<<<2688, 256, 0, stream>>>(x, W, a1, a2, adj, (u8*)adjw, hT, Aarr, Barr, Cexp, Dexp, Dsum);
  k_colsum<<<dim3(32, 16), 256, 0, stream>>>(adjw, Aarr, Barr, Cexp, Dexp, Dsum);
  k_pv<<<dim3(16, 16), 512, 0, stream>>>(adjw, hT, Aarr, Barr, Cexp, Dexp, Dsum, cat);
  k_out<<<128, 256, 0, stream>>>(cat, Wl, bl, out);
}

// Round 15
// 69.531 us; speedup vs baseline: 1.0492x; 1.0454x over previous
//
#include <hip/hip_runtime.h>
#include <hip/hip_bf16.h>
#include <stdint.h>

typedef __attribute__((ext_vector_type(8))) short short8;
typedef __attribute__((ext_vector_type(4))) float f32x4;
typedef _Float16 f16;
typedef __attribute__((ext_vector_type(8))) f16 f16x8;
typedef __attribute__((ext_vector_type(2))) f16 f16x2;
typedef uint32_t u32;
typedef uint16_t u16;
typedef uint8_t u8;

#define LOG2E 1.4426950408889634f

// B=4, N=2048, Cin=256, F=64, H=4
// Pipeline (4 kernels) — R12 (proven 70.0us) + pv double-buffered staging (T14):
//  K1 k_front : proj (x@W per head via MFMA; W transposed block-locally in LDS,
//               XOR-swizzled, b64-vectorized writes) + fused exact-fp32 fdots
//               -> Aarr/Barr/Cexp/Dexp || pack adj bits || zero Dsum; hT in FP16
//  K2 k_colsum: (jt, iseg) = 64 j x 128 i x 16 bh; atomicAdd Dsum
//  K3 k_pv    : fp16 packed P; CD (x16/D) inline in LDS; 128 i/block, j-split;
//               DOUBLE-BUFFERED hT staging (regs->LDS, 1 barrier/tile) -> bf16 partials
//  K4 k_out   : out = leaky((relu(p0+p1) @ Wl^T) + bl); p bf16
//
// ws layout (bytes):
//  adjw : 0x0000000 u32[2048*64]        512KB packed adjacency bits
//  hT   : 0x0080000 fp16[16][64][2048]    4MB per-(b,h) h transposed [f][n]
//  part : 0x0480000 bf16[2][4][2048][256] 8MB pv partials (2 j-halves)
//  Aarr : 0x1480000 f32[16][2048]       128KB exp(f1)
//  Barr : 0x14A0000 f32                 128KB exp(0.2*f1)
//  Cexp : 0x14C0000 f32                 128KB exp(f2)
//  Dexp : 0x14E0000 f32                 128KB exp(0.2*f2)
//  Dsum : 0x1500000 f32[16][2048]       128KB column sums (atomic)

__device__ __forceinline__ u16 f2bf(float f){
  union{float f; u32 u;} x; x.f = f;
  u32 r = x.u + 0x7FFFu + ((x.u >> 16) & 1u);
  return (u16)(r >> 16);
}
__device__ __forceinline__ u32 pkbf(float a, float b){
  __hip_bfloat162 h = __float22bfloat162_rn(float2{a, b});
  union{ __hip_bfloat162 h; u32 u; } cv; cv.h = h;
  return cv.u;
}
__device__ __forceinline__ u32 pkh(float a, float b){
  f16x2 h; h.x = (f16)a; h.y = (f16)b;
  union{ f16x2 h; u32 u; } cv; cv.h = h;
  return cv.u;
}
__device__ __forceinline__ f16x2 uh2(u32 x){ union{u32 u; f16x2 h;} v; v.u = x; return v.h; }
__device__ __forceinline__ u32 h2u(f16x2 x){ union{f16x2 h; u32 u;} v; v.h = x; return v.u; }

// ---------------- K1: proj(+fdots) || pack || zero Dsum ----------------
__global__ __launch_bounds__(256) void k_front(const float* __restrict__ x,
      const float* __restrict__ W, const float* __restrict__ a1, const float* __restrict__ a2,
      const int* __restrict__ adj,
      u8* __restrict__ adjb, u16* __restrict__ hT,
      float* __restrict__ Aarr, float* __restrict__ Barr,
      float* __restrict__ Cexp, float* __restrict__ Dexp,
      float* __restrict__ Dsum){
  int bid = blockIdx.x, t = threadIdx.x;

  if (bid >= 2560){                   // ---- zero Dsum ----
    Dsum[(bid - 2560)*256 + t] = 0.f;
    return;
  }
  if (bid >= 512){                    // ---- pack: 8 adj elems -> 1 byte ----
    int idx = (bid - 512)*256 + t;
    const int4* ap = (const int4*)(adj + (size_t)idx*8);
    int4 v0 = ap[0], v1 = ap[1];
    u32 byte = (u32)(v0.x > 0)        | ((u32)(v0.y > 0) << 1)
             | ((u32)(v0.z > 0) << 2) | ((u32)(v0.w > 0) << 3)
             | ((u32)(v1.x > 0) << 4) | ((u32)(v1.y > 0) << 5)
             | ((u32)(v1.z > 0) << 6) | ((u32)(v1.w > 0) << 7);
    adjb[idx] = (u8)byte;
    return;
  }
  // ---- proj: h = x @ W[head cb]; vectorized W transpose in LDS, XOR-swizzled ----
  __shared__ u16 WL[64*264];
  int rt = bid & 127, cb = bid >> 7;
  const float* Wh = W + (size_t)cb*16384;     // [256 c][64 f]
  {
    int f0 = (t & 15)*4;
    int cg = t >> 4;
    int s = ((f0 >> 2) & 7) << 3;
    #pragma unroll
    for (int it2 = 0; it2 < 4; it2++){
      int c0 = (cg + it2*16)*4;
      float4 wv0 = *(const float4*)(Wh + (size_t)(c0+0)*64 + f0);
      float4 wv1 = *(const float4*)(Wh + (size_t)(c0+1)*64 + f0);
      float4 wv2 = *(const float4*)(Wh + (size_t)(c0+2)*64 + f0);
      float4 wv3 = *(const float4*)(Wh + (size_t)(c0+3)*64 + f0);
      int cc = c0 ^ s;
      #pragma unroll
      for (int k = 0; k < 4; k++){
        u32 lo = pkbf((&wv0.x)[k], (&wv1.x)[k]);
        u32 hi = pkbf((&wv2.x)[k], (&wv3.x)[k]);
        *(uint2*)&WL[(f0+k)*264 + cc] = uint2{lo, hi};
      }
    }
  }
  __syncthreads();

  int w = t >> 6, l = t & 63;
  int rA = rt*64 + w*16 + (l & 15);
  int kg = (l >> 4) * 8;
  int rowq[4], rswq[4];
  #pragma unroll
  for (int q = 0; q < 4; q++){
    rowq[q] = q*16 + (l & 15);
    rswq[q] = ((rowq[q] >> 2) & 7) << 3;
  }
  f32x4 acc[4] = {};
  const float* xrow = x + (size_t)rA * 256;
  #pragma unroll
  for (int ks = 0; ks < 8; ks++){
    int c = ks*32 + kg;
    float4 xa = *(const float4*)(xrow + c);
    float4 xb = *(const float4*)(xrow + c + 4);
    union{u32 w[4]; short8 v;} A;
    A.w[0] = pkbf(xa.x, xa.y); A.w[1] = pkbf(xa.z, xa.w);
    A.w[2] = pkbf(xb.x, xb.y); A.w[3] = pkbf(xb.z, xb.w);
    #pragma unroll
    for (int q = 0; q < 4; q++){
      short8 Bf = *(const short8*)&WL[rowq[q]*264 + (c ^ rswq[q])];
      acc[q] = __builtin_amdgcn_mfma_f32_16x16x32_bf16(A.v, Bf, acc[q], 0, 0, 0);
    }
  }
  int rb = rt*64 + w*16 + (l >> 4)*4;
  int b = rb >> 11, n = rb & 2047;
  #pragma unroll
  for (int q = 0; q < 4; q++){
    int f = q*16 + (l & 15);
    u32 p0 = pkh(acc[q][0], acc[q][1]);
    u32 p1 = pkh(acc[q][2], acc[q][3]);
    u16* dst = hT + ((size_t)(b*4 + cb)*64 + f)*2048 + n;
    *(uint2*)dst = uint2{p0, p1};
  }
  float a1v[4], a2v[4];
  #pragma unroll
  for (int q = 0; q < 4; q++){
    a1v[q] = a1[cb*64 + q*16 + (l & 15)];
    a2v[q] = a2[cb*64 + q*16 + (l & 15)];
  }
  float s1[4], s2[4];
  #pragma unroll
  for (int r = 0; r < 4; r++){
    s1[r] = acc[0][r]*a1v[0] + acc[1][r]*a1v[1] + acc[2][r]*a1v[2] + acc[3][r]*a1v[3];
    s2[r] = acc[0][r]*a2v[0] + acc[1][r]*a2v[1] + acc[2][r]*a2v[2] + acc[3][r]*a2v[3];
  }
  #pragma unroll
  for (int m = 1; m <= 8; m <<= 1){
    #pragma unroll
    for (int r = 0; r < 4; r++){
      s1[r] += __shfl_xor(s1[r], m);
      s2[r] += __shfl_xor(s2[r], m);
    }
  }
  if ((l & 15) == 0){
    #pragma unroll
    for (int r = 0; r < 4; r++){
      int row = rb + r;
      int bb = row >> 11, nn = row & 2047;
      int o = (bb*4 + cb)*2048 + nn;
      float fa = s1[r] * LOG2E;
      Aarr[o] = __builtin_amdgcn_exp2f(fa);
      Barr[o] = __builtin_amdgcn_exp2f(0.2f*fa);
      float fb = s2[r] * LOG2E;
      Cexp[o] = __builtin_amdgcn_exp2f(fb);
      Dexp[o] = __builtin_amdgcn_exp2f(0.2f*fb);
    }
  }
}

// ---------------- K2: colsum (R12-proven form) -> atomic Dsum ----------------
__global__ __launch_bounds__(256) void k_colsum(const u32* __restrict__ adjw,
      const float* __restrict__ Aarr, const float* __restrict__ Barr,
      const float* __restrict__ Cexp, const float* __restrict__ Dexp,
      float* __restrict__ Dsum){
  __shared__ float AL[128*16], BL[128*16];
  __shared__ float red[4][1024];
  int jt = blockIdx.x;      // 32 j-tiles of 64
  int is = blockIdx.y;      // 16 i-segments of 128
  int t = threadIdx.x, w = t >> 6, l = t & 63;
  int i0 = is*128;
  for (int k = t; k < 2048; k += 256){
    int bh = k >> 7, ii = k & 127;
    AL[ii*16 + bh] = Aarr[bh*2048 + i0 + ii];
    BL[ii*16 + bh] = Barr[bh*2048 + i0 + ii];
  }
  int j = jt*64 + l;
  float Cj[16], Dj[16];
  #pragma unroll
  for (int bh = 0; bh < 16; bh++){
    Cj[bh] = Cexp[bh*2048 + j];
    Dj[bh] = Dexp[bh*2048 + j];
  }
  float acc[16] = {};
  __syncthreads();
  int wi = jt*2 + (l >> 5), sh = l & 31;
  const u32* aw = adjw + wi;
  #pragma unroll 2
  for (int ii = w*32; ii < w*32 + 32; ii++){
    u32 m = aw[(size_t)(i0 + ii)*64];
    float bitf = (float)((m >> sh) & 1u);
    const float* ar = &AL[ii*16];
    const float* br = &BL[ii*16];
    #pragma unroll
    for (int q = 0; q < 4; q++){
      float4 a4 = *(const float4*)(ar + q*4);
      float4 b4 = *(const float4*)(br + q*4);
      acc[q*4+0] = fmaf(fmaxf(a4.x*Cj[q*4+0], b4.x*Dj[q*4+0]), bitf, acc[q*4+0]);
      acc[q*4+1] = fmaf(fmaxf(a4.y*Cj[q*4+1], b4.y*Dj[q*4+1]), bitf, acc[q*4+1]);
      acc[q*4+2] = fmaf(fmaxf(a4.z*Cj[q*4+2], b4.z*Dj[q*4+2]), bitf, acc[q*4+2]);
      acc[q*4+3] = fmaf(fmaxf(a4.w*Cj[q*4+3], b4.w*Dj[q*4+3]), bitf, acc[q*4+3]);
    }
  }
  #pragma unroll
  for (int bh = 0; bh < 16; bh++) red[w][bh*64 + l] = acc[bh];
  __syncthreads();
  #pragma unroll
  for (int k = 0; k < 4; k++){
    int e = t*4 + k;
    float s = (red[0][e] + red[1][e]) + (red[2][e] + red[3][e]);
    int bh = e >> 6, jl = e & 63;
    atomicAdd(&Dsum[bh*2048 + jt*64 + jl], s);
  }
}

// ---------------- K3: fused PV, fp16 packed P, double-buffered staging ----------------
__global__ __launch_bounds__(256) void k_pv(const u32* __restrict__ adjw, const u16* __restrict__ hT,
      const float* __restrict__ Aarr, const float* __restrict__ Barr,
      const float* __restrict__ Cexp, const float* __restrict__ Dexp,
      const float* __restrict__ Dsum, u16* __restrict__ part){
  int it = blockIdx.x;           // 16 i-tiles of 128
  int bh = blockIdx.y;           // 16
  int jh = blockIdx.z;           // 2 j-halves
  int b = bh >> 2, h = bh & 3;
  int t = threadIdx.x;
  int w = t >> 6, l = t & 63;

  __shared__ u16 hTl[2][64*136]; // 34.8KB double-buffered fp16 [f][j] stride 136
  __shared__ u32 CA2l[512];      // fp16x2 pairs: Ca*16/D for (2j,2j+1)
  __shared__ u32 DB2l[512];

  {  // inline CD (scaled x16): 4 j per thread
    int gj = bh*2048 + jh*1024 + t*4;
    float4 c4 = *(const float4*)(Cexp + gj);
    float4 d4 = *(const float4*)(Dexp + gj);
    float4 s4 = *(const float4*)(Dsum + gj);
    float i0v = 16.0f/s4.x, i1v = 16.0f/s4.y, i2v = 16.0f/s4.z, i3v = 16.0f/s4.w;
    CA2l[t*2]   = pkh(c4.x*i0v, c4.y*i1v);
    CA2l[t*2+1] = pkh(c4.z*i2v, c4.w*i3v);
    DB2l[t*2]   = pkh(d4.x*i0v, d4.y*i1v);
    DB2l[t*2+1] = pkh(d4.z*i2v, d4.w*i3v);
  }

  int i0 = it*128 + w*32 + (l & 15);  // row-block 0; row-block 1 = i0+16
  f16x2 Ai02, Bi02, Ai12, Bi12;
  {
    const float sc = 0.0625f;   // 1/16
    float A0 = Aarr[bh*2048 + i0] * sc,      B0 = Barr[bh*2048 + i0] * sc;
    float A1 = Aarr[bh*2048 + i0 + 16] * sc, B1 = Barr[bh*2048 + i0 + 16] * sc;
    Ai02 = uh2(pkh(A0, A0)); Bi02 = uh2(pkh(B0, B0));
    Ai12 = uh2(pkh(A1, A1)); Bi12 = uh2(pkh(B1, B1));
  }
  const u16* hTr = hT + (size_t)bh * 64 * 2048;
  int kg = (l >> 4) * 8;
  f32x4 acc[2][4] = {};

  int sf = t >> 2, sseg = (t & 3) * 32;        // staging role: row, 32-u16 segment
  const u16* srcbase = hTr + (size_t)sf*2048 + sseg + jh*1024;
  uint4 r0, r1, r2, r3;
  {  // prologue: stage tile 0 into buf 0
    const u16* src = srcbase;
    r0 = *(const uint4*)(src);      r1 = *(const uint4*)(src + 8);
    r2 = *(const uint4*)(src + 16); r3 = *(const uint4*)(src + 24);
    u16* d = &hTl[0][sf*136 + sseg];
    *(uint4*)(d) = r0; *(uint4*)(d + 8) = r1; *(uint4*)(d + 16) = r2; *(uint4*)(d + 24) = r3;
  }
  int cur = 0;

  for (int jj = 0; jj < 1024; jj += 128){
    int jc = jh*1024 + jj;
    __syncthreads();                 // buf[cur] ready for reads
    bool more = (jj + 128) < 1024;
    if (more){                       // issue next tile's loads; they fly during compute
      const u16* src = srcbase + jj + 128;
      r0 = *(const uint4*)(src);      r1 = *(const uint4*)(src + 8);
      r2 = *(const uint4*)(src + 16); r3 = *(const uint4*)(src + 24);
    }
    uint4 mw0 = *(const uint4*)(adjw + (size_t)i0*64 + (jc >> 5));
    uint4 mw1 = *(const uint4*)(adjw + (size_t)(i0+16)*64 + (jc >> 5));
    const u16* hbuf = hTl[cur];
    #pragma unroll
    for (int ks = 0; ks < 4; ks++){
      int pbase = (jj >> 1) + ks*16 + (l >> 4)*4;
      uint4 ca2 = *(const uint4*)&CA2l[pbase];
      uint4 db2 = *(const uint4*)&DB2l[pbase];
      u32 w0 = (&mw0.x)[ks] >> kg;
      u32 w1 = (&mw1.x)[ks] >> kg;
      union{u32 w[4]; f16x8 v;} A0u, A1u;
      #pragma unroll
      for (int p = 0; p < 4; p++){
        f16x2 cav = uh2((&ca2.x)[p]);
        f16x2 dbv = uh2((&db2.x)[p]);
        f16x2 e0 = __builtin_elementwise_max(Ai02*cav, Bi02*dbv);
        f16x2 e1 = __builtin_elementwise_max(Ai12*cav, Bi12*dbv);
        u32 m0 = ((u32)((int)(w0 << (31-2*p)) >> 31) & 0x0000FFFFu)
               | ((u32)((int)(w0 << (30-2*p)) >> 31) & 0xFFFF0000u);
        u32 m1 = ((u32)((int)(w1 << (31-2*p)) >> 31) & 0x0000FFFFu)
               | ((u32)((int)(w1 << (30-2*p)) >> 31) & 0xFFFF0000u);
        A0u.w[p] = h2u(e0) & m0;
        A1u.w[p] = h2u(e1) & m1;
      }
      #pragma unroll
      for (int q = 0; q < 4; q++){
        f16x8 Bf = *(const f16x8*)&hbuf[(q*16 + (l & 15))*136 + ks*32 + kg];
        acc[0][q] = __builtin_amdgcn_mfma_f32_16x16x32_f16(A0u.v, Bf, acc[0][q], 0, 0, 0);
        acc[1][q] = __builtin_amdgcn_mfma_f32_16x16x32_f16(A1u.v, Bf, acc[1][q], 0, 0, 0);
      }
    }
    if (more){                       // write next tile into alternate buffer
      u16* d = &hTl[cur ^ 1][sf*136 + sseg];
      *(uint4*)(d) = r0; *(uint4*)(d + 8) = r1; *(uint4*)(d + 16) = r2; *(uint4*)(d + 24) = r3;
      cur ^= 1;
    }
  }
  // epilogue: write bf16 partial [jh][b][n][h*64+f]
  u16* pr = part + ((size_t)(jh*4 + b)*2048)*256;
  #pragma unroll
  for (int r = 0; r < 2; r++){
    int nb = it*128 + w*32 + r*16 + (l >> 4)*4;
    #pragma unroll
    for (int q = 0; q < 4; q++){
      int f = h*64 + q*16 + (l & 15);
      #pragma unroll
      for (int rr = 0; rr < 4; rr++){
        pr[(size_t)(nb + rr)*256 + f] = f2bf(acc[r][q][rr]);
      }
    }
  }
}

// ---------------- K4: out = leaky(relu(p0+p1) @ Wl^T + bl); p bf16 ----------------
__global__ __launch_bounds__(256) void k_out(const u16* __restrict__ part,
                       const float* __restrict__ Wl, const float* __restrict__ bl,
                       float* __restrict__ out){
  int rt = blockIdx.x;
  int w = threadIdx.x >> 6, l = threadIdx.x & 63;
  int rA = rt*64 + w*16 + (l & 15);
  int b = rA >> 11, n = rA & 2047;
  const u16* p0 = part + ((size_t)b*2048 + n)*256;
  const u16* p1 = part + ((size_t)(4 + b)*2048 + n)*256;
  int kg = (l >> 4) * 8;
  f32x4 acc[4] = {};
  #pragma unroll
  for (int ks = 0; ks < 8; ks++){
    int c = ks*32 + kg;
    short8 v0 = *(const short8*)(p0 + c);
    short8 v1 = *(const short8*)(p1 + c);
    float av[8];
    #pragma unroll
    for (int e = 0; e < 8; e++){
      union{u32 u; float f;} x0, x1;
      x0.u = ((u32)(u16)v0[e]) << 16;
      x1.u = ((u32)(u16)v1[e]) << 16;
      av[e] = fmaxf(x0.f + x1.f, 0.f);
    }
    union{u32 w[4]; short8 v;} A;
    A.w[0] = pkbf(av[0], av[1]); A.w[1] = pkbf(av[2], av[3]);
    A.w[2] = pkbf(av[4], av[5]); A.w[3] = pkbf(av[6], av[7]);
    #pragma unroll
    for (int q = 0; q < 4; q++){
      const float* wr = Wl + (size_t)(q*16 + (l & 15))*256 + c;
      float4 u0 = *(const float4*)(wr);
      float4 u1 = *(const float4*)(wr + 4);
      union{u32 w[4]; short8 v;} Bv;
      Bv.w[0] = pkbf(u0.x, u0.y); Bv.w[1] = pkbf(u0.z, u0.w);
      Bv.w[2] = pkbf(u1.x, u1.y); Bv.w[3] = pkbf(u1.z, u1.w);
      acc[q] = __builtin_amdgcn_mfma_f32_16x16x32_bf16(A.v, Bv.v, acc[q], 0, 0, 0);
    }
  }
  int rb = rt*64 + w*16 + (l >> 4)*4;
  #pragma unroll
  for (int q = 0; q < 4; q++){
    int o = q*16 + (l & 15);
    float bv = bl[o];
    #pragma unroll
    for (int r = 0; r < 4; r++){
      float v = acc[q][r] + bv;
      out[(size_t)(rb + r)*64 + o] = fmaxf(v, 0.2f*v);
    }
  }
}

extern "C" void kernel_launch(void* const* d_in, const int* in_sizes, int n_in,
                              void* d_out, int out_size, void* d_ws, size_t ws_size,
                              hipStream_t stream) {
  const float* x  = (const float*)d_in[0];
  const int* adj  = (const int*)d_in[1];
  const float* W  = (const float*)d_in[2];
  const float* a1 = (const float*)d_in[3];
  const float* a2 = (const float*)d_in[4];
  const float* Wl = (const float*)d_in[5];
  const float* bl = (const float*)d_in[6];
  float* out = (float*)d_out;
  char* ws = (char*)d_ws;

  u32* adjw    = (u32*)(ws + 0x0000000);
  u16* hT      = (u16*)(ws + 0x0080000);
  u16* part    = (u16*)(ws + 0x0480000);
  float* Aarr  = (float*)(ws + 0x1480000);
  float* Barr  = (float*)(ws + 0x14A0000);
  float* Cexp  = (float*)(ws + 0x14C0000);
  float* Dexp  = (float*)(ws + 0x14E0000);
  float* Dsum  = (float*)(ws + 0x1500000);

  k_front<<<2688, 256, 0, stream>>>(x, W, a1, a2, adj, (u8*)adjw, hT, Aarr, Barr, Cexp, Dexp, Dsum);
  k_colsum<<<dim3(32, 16), 256, 0, stream>>>(adjw, Aarr, Barr, Cexp, Dexp, Dsum);
  k_pv<<<dim3(16, 16, 2), 256, 0, stream>>>(adjw, hT, Aarr, Barr, Cexp, Dexp, Dsum, part);
  k_out<<<128, 256, 0, stream>>>(part, Wl, bl, out);
}

// Round 16
// 67.563 us; speedup vs baseline: 1.0798x; 1.0291x over previous
//
#include <hip/hip_runtime.h>
#include <hip/hip_bf16.h>
#include <stdint.h>

typedef __attribute__((ext_vector_type(8))) short short8;
typedef __attribute__((ext_vector_type(4))) float f32x4;
typedef _Float16 f16;
typedef __attribute__((ext_vector_type(8))) f16 f16x8;
typedef __attribute__((ext_vector_type(2))) f16 f16x2;
typedef uint32_t u32;
typedef uint16_t u16;
typedef uint8_t u8;

#define LOG2E 1.4426950408889634f

// B=4, N=2048, Cin=256, F=64, H=4
// Pipeline (4 kernels) — R15 (69.5us) + XCD-chunked swizzles + k_out full-chip:
//  K1 k_front : proj (x@W per head; XCD-chunked: each XCD owns 16 rt x 4 cb for
//               x L2-locality) + exact-fp32 fdots || pack adj || zero Dsum; hT FP16
//  K2 k_colsum: (jt, iseg) = 64 j x 128 i x 16 bh; atomicAdd Dsum
//  K3 k_pv    : 1D grid 512, XCD-chunked (2 bh panels per XCD -> hT L2-resident);
//               fp16 packed P; CD (x16/D) in LDS; dbuf staging -> bf16 partials
//  K4 k_out   : 256 blocks x 128 thr (all CUs; 2 waves; 32 rows/block)
//
// ws layout (bytes):
//  adjw : 0x0000000 u32[2048*64]        512KB packed adjacency bits
//  hT   : 0x0080000 fp16[16][64][2048]    4MB per-(b,h) h transposed [f][n]
//  part : 0x0480000 bf16[2][4][2048][256] 8MB pv partials (2 j-halves)
//  Aarr : 0x1480000 f32[16][2048]       128KB exp(f1)
//  Barr : 0x14A0000 f32                 128KB exp(0.2*f1)
//  Cexp : 0x14C0000 f32                 128KB exp(f2)
//  Dexp : 0x14E0000 f32                 128KB exp(0.2*f2)
//  Dsum : 0x1500000 f32[16][2048]       128KB column sums (atomic)

__device__ __forceinline__ u16 f2bf(float f){
  union{float f; u32 u;} x; x.f = f;
  u32 r = x.u + 0x7FFFu + ((x.u >> 16) & 1u);
  return (u16)(r >> 16);
}
__device__ __forceinline__ u32 pkbf(float a, float b){
  __hip_bfloat162 h = __float22bfloat162_rn(float2{a, b});
  union{ __hip_bfloat162 h; u32 u; } cv; cv.h = h;
  return cv.u;
}
__device__ __forceinline__ u32 pkh(float a, float b){
  f16x2 h; h.x = (f16)a; h.y = (f16)b;
  union{ f16x2 h; u32 u; } cv; cv.h = h;
  return cv.u;
}
__device__ __forceinline__ f16x2 uh2(u32 x){ union{u32 u; f16x2 h;} v; v.u = x; return v.h; }
__device__ __forceinline__ u32 h2u(f16x2 x){ union{f16x2 h; u32 u;} v; v.h = x; return v.u; }

// ---------------- K1: proj(+fdots) || pack || zero Dsum ----------------
__global__ __launch_bounds__(256) void k_front(const float* __restrict__ x,
      const float* __restrict__ W, const float* __restrict__ a1, const float* __restrict__ a2,
      const int* __restrict__ adj,
      u8* __restrict__ adjb, u16* __restrict__ hT,
      float* __restrict__ Aarr, float* __restrict__ Barr,
      float* __restrict__ Cexp, float* __restrict__ Dexp,
      float* __restrict__ Dsum){
  int bid = blockIdx.x, t = threadIdx.x;

  if (bid >= 2560){                   // ---- zero Dsum ----
    Dsum[(bid - 2560)*256 + t] = 0.f;
    return;
  }
  if (bid >= 512){                    // ---- pack: 8 adj elems -> 1 byte ----
    int idx = (bid - 512)*256 + t;
    const int4* ap = (const int4*)(adj + (size_t)idx*8);
    int4 v0 = ap[0], v1 = ap[1];
    u32 byte = (u32)(v0.x > 0)        | ((u32)(v0.y > 0) << 1)
             | ((u32)(v0.z > 0) << 2) | ((u32)(v0.w > 0) << 3)
             | ((u32)(v1.x > 0) << 4) | ((u32)(v1.y > 0) << 5)
             | ((u32)(v1.z > 0) << 6) | ((u32)(v1.w > 0) << 7);
    adjb[idx] = (u8)byte;
    return;
  }
  // ---- proj; XCD-chunked swizzle: xcd = bid&7 owns rt chunk of 16 x all 4 cb ----
  __shared__ u16 WL[64*264];
  int xcd = bid & 7, slot = bid >> 3;          // bijective: 512 = 8 x 64
  int rt = xcd*16 + (slot & 15);
  int cb = slot >> 4;
  const float* Wh = W + (size_t)cb*16384;     // [256 c][64 f]
  {
    int f0 = (t & 15)*4;
    int cg = t >> 4;
    int s = ((f0 >> 2) & 7) << 3;
    #pragma unroll
    for (int it2 = 0; it2 < 4; it2++){
      int c0 = (cg + it2*16)*4;
      float4 wv0 = *(const float4*)(Wh + (size_t)(c0+0)*64 + f0);
      float4 wv1 = *(const float4*)(Wh + (size_t)(c0+1)*64 + f0);
      float4 wv2 = *(const float4*)(Wh + (size_t)(c0+2)*64 + f0);
      float4 wv3 = *(const float4*)(Wh + (size_t)(c0+3)*64 + f0);
      int cc = c0 ^ s;
      #pragma unroll
      for (int k = 0; k < 4; k++){
        u32 lo = pkbf((&wv0.x)[k], (&wv1.x)[k]);
        u32 hi = pkbf((&wv2.x)[k], (&wv3.x)[k]);
        *(uint2*)&WL[(f0+k)*264 + cc] = uint2{lo, hi};
      }
    }
  }
  __syncthreads();

  int w = t >> 6, l = t & 63;
  int rA = rt*64 + w*16 + (l & 15);
  int kg = (l >> 4) * 8;
  int rowq[4], rswq[4];
  #pragma unroll
  for (int q = 0; q < 4; q++){
    rowq[q] = q*16 + (l & 15);
    rswq[q] = ((rowq[q] >> 2) & 7) << 3;
  }
  f32x4 acc[4] = {};
  const float* xrow = x + (size_t)rA * 256;
  #pragma unroll
  for (int ks = 0; ks < 8; ks++){
    int c = ks*32 + kg;
    float4 xa = *(const float4*)(xrow + c);
    float4 xb = *(const float4*)(xrow + c + 4);
    union{u32 w[4]; short8 v;} A;
    A.w[0] = pkbf(xa.x, xa.y); A.w[1] = pkbf(xa.z, xa.w);
    A.w[2] = pkbf(xb.x, xb.y); A.w[3] = pkbf(xb.z, xb.w);
    #pragma unroll
    for (int q = 0; q < 4; q++){
      short8 Bf = *(const short8*)&WL[rowq[q]*264 + (c ^ rswq[q])];
      acc[q] = __builtin_amdgcn_mfma_f32_16x16x32_bf16(A.v, Bf, acc[q], 0, 0, 0);
    }
  }
  int rb = rt*64 + w*16 + (l >> 4)*4;
  int b = rb >> 11, n = rb & 2047;
  #pragma unroll
  for (int q = 0; q < 4; q++){
    int f = q*16 + (l & 15);
    u32 p0 = pkh(acc[q][0], acc[q][1]);
    u32 p1 = pkh(acc[q][2], acc[q][3]);
    u16* dst = hT + ((size_t)(b*4 + cb)*64 + f)*2048 + n;
    *(uint2*)dst = uint2{p0, p1};
  }
  float a1v[4], a2v[4];
  #pragma unroll
  for (int q = 0; q < 4; q++){
    a1v[q] = a1[cb*64 + q*16 + (l & 15)];
    a2v[q] = a2[cb*64 + q*16 + (l & 15)];
  }
  float s1[4], s2[4];
  #pragma unroll
  for (int r = 0; r < 4; r++){
    s1[r] = acc[0][r]*a1v[0] + acc[1][r]*a1v[1] + acc[2][r]*a1v[2] + acc[3][r]*a1v[3];
    s2[r] = acc[0][r]*a2v[0] + acc[1][r]*a2v[1] + acc[2][r]*a2v[2] + acc[3][r]*a2v[3];
  }
  #pragma unroll
  for (int m = 1; m <= 8; m <<= 1){
    #pragma unroll
    for (int r = 0; r < 4; r++){
      s1[r] += __shfl_xor(s1[r], m);
      s2[r] += __shfl_xor(s2[r], m);
    }
  }
  if ((l & 15) == 0){
    #pragma unroll
    for (int r = 0; r < 4; r++){
      int row = rb + r;
      int bb = row >> 11, nn = row & 2047;
      int o = (bb*4 + cb)*2048 + nn;
      float fa = s1[r] * LOG2E;
      Aarr[o] = __builtin_amdgcn_exp2f(fa);
      Barr[o] = __builtin_amdgcn_exp2f(0.2f*fa);
      float fb = s2[r] * LOG2E;
      Cexp[o] = __builtin_amdgcn_exp2f(fb);
      Dexp[o] = __builtin_amdgcn_exp2f(0.2f*fb);
    }
  }
}

// ---------------- K2: colsum (R12-proven form) -> atomic Dsum ----------------
__global__ __launch_bounds__(256) void k_colsum(const u32* __restrict__ adjw,
      const float* __restrict__ Aarr, const float* __restrict__ Barr,
      const float* __restrict__ Cexp, const float* __restrict__ Dexp,
      float* __restrict__ Dsum){
  __shared__ float AL[128*16], BL[128*16];
  __shared__ float red[4][1024];
  int jt = blockIdx.x;      // 32 j-tiles of 64
  int is = blockIdx.y;      // 16 i-segments of 128
  int t = threadIdx.x, w = t >> 6, l = t & 63;
  int i0 = is*128;
  for (int k = t; k < 2048; k += 256){
    int bh = k >> 7, ii = k & 127;
    AL[ii*16 + bh] = Aarr[bh*2048 + i0 + ii];
    BL[ii*16 + bh] = Barr[bh*2048 + i0 + ii];
  }
  int j = jt*64 + l;
  float Cj[16], Dj[16];
  #pragma unroll
  for (int bh = 0; bh < 16; bh++){
    Cj[bh] = Cexp[bh*2048 + j];
    Dj[bh] = Dexp[bh*2048 + j];
  }
  float acc[16] = {};
  __syncthreads();
  int wi = jt*2 + (l >> 5), sh = l & 31;
  const u32* aw = adjw + wi;
  #pragma unroll 2
  for (int ii = w*32; ii < w*32 + 32; ii++){
    u32 m = aw[(size_t)(i0 + ii)*64];
    float bitf = (float)((m >> sh) & 1u);
    const float* ar = &AL[ii*16];
    const float* br = &BL[ii*16];
    #pragma unroll
    for (int q = 0; q < 4; q++){
      float4 a4 = *(const float4*)(ar + q*4);
      float4 b4 = *(const float4*)(br + q*4);
      acc[q*4+0] = fmaf(fmaxf(a4.x*Cj[q*4+0], b4.x*Dj[q*4+0]), bitf, acc[q*4+0]);
      acc[q*4+1] = fmaf(fmaxf(a4.y*Cj[q*4+1], b4.y*Dj[q*4+1]), bitf, acc[q*4+1]);
      acc[q*4+2] = fmaf(fmaxf(a4.z*Cj[q*4+2], b4.z*Dj[q*4+2]), bitf, acc[q*4+2]);
      acc[q*4+3] = fmaf(fmaxf(a4.w*Cj[q*4+3], b4.w*Dj[q*4+3]), bitf, acc[q*4+3]);
    }
  }
  #pragma unroll
  for (int bh = 0; bh < 16; bh++) red[w][bh*64 + l] = acc[bh];
  __syncthreads();
  #pragma unroll
  for (int k = 0; k < 4; k++){
    int e = t*4 + k;
    float s = (red[0][e] + red[1][e]) + (red[2][e] + red[3][e]);
    int bh = e >> 6, jl = e & 63;
    atomicAdd(&Dsum[bh*2048 + jt*64 + jl], s);
  }
}

// ---------------- K3: fused PV, fp16 packed P, dbuf staging, XCD-chunked ----------------
__global__ __launch_bounds__(256) void k_pv(const u32* __restrict__ adjw, const u16* __restrict__ hT,
      const float* __restrict__ Aarr, const float* __restrict__ Barr,
      const float* __restrict__ Cexp, const float* __restrict__ Dexp,
      const float* __restrict__ Dsum, u16* __restrict__ part){
  // XCD-chunked: xcd = hw&7 owns 64 consecutive works = 2 bh panels
  int hw = blockIdx.x;
  int work = (hw & 7)*64 + (hw >> 3);     // bijective: 512 = 8 x 64
  int bh = work >> 5;                     // 2 bh per XCD
  int jh = (work >> 4) & 1;
  int it = work & 15;
  int b = bh >> 2, h = bh & 3;
  int t = threadIdx.x;
  int w = t >> 6, l = t & 63;

  __shared__ u16 hTl[2][64*136]; // 34.8KB double-buffered fp16 [f][j] stride 136
  __shared__ u32 CA2l[512];      // fp16x2 pairs: Ca*16/D for (2j,2j+1)
  __shared__ u32 DB2l[512];

  {  // inline CD (scaled x16): 4 j per thread
    int gj = bh*2048 + jh*1024 + t*4;
    float4 c4 = *(const float4*)(Cexp + gj);
    float4 d4 = *(const float4*)(Dexp + gj);
    float4 s4 = *(const float4*)(Dsum + gj);
    float i0v = 16.0f/s4.x, i1v = 16.0f/s4.y, i2v = 16.0f/s4.z, i3v = 16.0f/s4.w;
    CA2l[t*2]   = pkh(c4.x*i0v, c4.y*i1v);
    CA2l[t*2+1] = pkh(c4.z*i2v, c4.w*i3v);
    DB2l[t*2]   = pkh(d4.x*i0v, d4.y*i1v);
    DB2l[t*2+1] = pkh(d4.z*i2v, d4.w*i3v);
  }

  int i0 = it*128 + w*32 + (l & 15);  // row-block 0; row-block 1 = i0+16
  f16x2 Ai02, Bi02, Ai12, Bi12;
  {
    const float sc = 0.0625f;   // 1/16
    float A0 = Aarr[bh*2048 + i0] * sc,      B0 = Barr[bh*2048 + i0] * sc;
    float A1 = Aarr[bh*2048 + i0 + 16] * sc, B1 = Barr[bh*2048 + i0 + 16] * sc;
    Ai02 = uh2(pkh(A0, A0)); Bi02 = uh2(pkh(B0, B0));
    Ai12 = uh2(pkh(A1, A1)); Bi12 = uh2(pkh(B1, B1));
  }
  const u16* hTr = hT + (size_t)bh * 64 * 2048;
  int kg = (l >> 4) * 8;
  f32x4 acc[2][4] = {};

  int sf = t >> 2, sseg = (t & 3) * 32;        // staging role: row, 32-u16 segment
  const u16* srcbase = hTr + (size_t)sf*2048 + sseg + jh*1024;
  uint4 r0, r1, r2, r3;
  {  // prologue: stage tile 0 into buf 0
    const u16* src = srcbase;
    r0 = *(const uint4*)(src);      r1 = *(const uint4*)(src + 8);
    r2 = *(const uint4*)(src + 16); r3 = *(const uint4*)(src + 24);
    u16* d = &hTl[0][sf*136 + sseg];
    *(uint4*)(d) = r0; *(uint4*)(d + 8) = r1; *(uint4*)(d + 16) = r2; *(uint4*)(d + 24) = r3;
  }
  int cur = 0;

  for (int jj = 0; jj < 1024; jj += 128){
    int jc = jh*1024 + jj;
    __syncthreads();                 // buf[cur] ready for reads
    bool more = (jj + 128) < 1024;
    if (more){                       // issue next tile's loads; they fly during compute
      const u16* src = srcbase + jj + 128;
      r0 = *(const uint4*)(src);      r1 = *(const uint4*)(src + 8);
      r2 = *(const uint4*)(src + 16); r3 = *(const uint4*)(src + 24);
    }
    uint4 mw0 = *(const uint4*)(adjw + (size_t)i0*64 + (jc >> 5));
    uint4 mw1 = *(const uint4*)(adjw + (size_t)(i0+16)*64 + (jc >> 5));
    const u16* hbuf = hTl[cur];
    #pragma unroll
    for (int ks = 0; ks < 4; ks++){
      int pbase = (jj >> 1) + ks*16 + (l >> 4)*4;
      uint4 ca2 = *(const uint4*)&CA2l[pbase];
      uint4 db2 = *(const uint4*)&DB2l[pbase];
      u32 w0 = (&mw0.x)[ks] >> kg;
      u32 w1 = (&mw1.x)[ks] >> kg;
      union{u32 w[4]; f16x8 v;} A0u, A1u;
      #pragma unroll
      for (int p = 0; p < 4; p++){
        f16x2 cav = uh2((&ca2.x)[p]);
        f16x2 dbv = uh2((&db2.x)[p]);
        f16x2 e0 = __builtin_elementwise_max(Ai02*cav, Bi02*dbv);
        f16x2 e1 = __builtin_elementwise_max(Ai12*cav, Bi12*dbv);
        u32 m0 = ((u32)((int)(w0 << (31-2*p)) >> 31) & 0x0000FFFFu)
               | ((u32)((int)(w0 << (30-2*p)) >> 31) & 0xFFFF0000u);
        u32 m1 = ((u32)((int)(w1 << (31-2*p)) >> 31) & 0x0000FFFFu)
               | ((u32)((int)(w1 << (30-2*p)) >> 31) & 0xFFFF0000u);
        A0u.w[p] = h2u(e0) & m0;
        A1u.w[p] = h2u(e1) & m1;
      }
      #pragma unroll
      for (int q = 0; q < 4; q++){
        f16x8 Bf = *(const f16x8*)&hbuf[(q*16 + (l & 15))*136 + ks*32 + kg];
        acc[0][q] = __builtin_amdgcn_mfma_f32_16x16x32_f16(A0u.v, Bf, acc[0][q], 0, 0, 0);
        acc[1][q] = __builtin_amdgcn_mfma_f32_16x16x32_f16(A1u.v, Bf, acc[1][q], 0, 0, 0);
      }
    }
    if (more){                       // write next tile into alternate buffer
      u16* d = &hTl[cur ^ 1][sf*136 + sseg];
      *(uint4*)(d) = r0; *(uint4*)(d + 8) = r1; *(uint4*)(d + 16) = r2; *(uint4*)(d + 24) = r3;
      cur ^= 1;
    }
  }
  // epilogue: write bf16 partial [jh][b][n][h*64+f]
  u16* pr = part + ((size_t)(jh*4 + b)*2048)*256;
  #pragma unroll
  for (int r = 0; r < 2; r++){
    int nb = it*128 + w*32 + r*16 + (l >> 4)*4;
    #pragma unroll
    for (int q = 0; q < 4; q++){
      int f = h*64 + q*16 + (l & 15);
      #pragma unroll
      for (int rr = 0; rr < 4; rr++){
        pr[(size_t)(nb + rr)*256 + f] = f2bf(acc[r][q][rr]);
      }
    }
  }
}

// ---------------- K4: out (256 blocks x 128 thr, all CUs) ----------------
__global__ __launch_bounds__(128) void k_out(const u16* __restrict__ part,
                       const float* __restrict__ Wl, const float* __restrict__ bl,
                       float* __restrict__ out){
  int rt = blockIdx.x;                  // 256 tiles of 32 rows
  int w = threadIdx.x >> 6, l = threadIdx.x & 63;
  int rA = rt*32 + w*16 + (l & 15);
  int b = rA >> 11, n = rA & 2047;
  const u16* p0 = part + ((size_t)b*2048 + n)*256;
  const u16* p1 = part + ((size_t)(4 + b)*2048 + n)*256;
  int kg = (l >> 4) * 8;
  f32x4 acc[4] = {};
  #pragma unroll
  for (int ks = 0; ks < 8; ks++){
    int c = ks*32 + kg;
    short8 v0 = *(const short8*)(p0 + c);
    short8 v1 = *(const short8*)(p1 + c);
    float av[8];
    #pragma unroll
    for (int e = 0; e < 8; e++){
      union{u32 u; float f;} x0, x1;
      x0.u = ((u32)(u16)v0[e]) << 16;
      x1.u = ((u32)(u16)v1[e]) << 16;
      av[e] = fmaxf(x0.f + x1.f, 0.f);
    }
    union{u32 w[4]; short8 v;} A;
    A.w[0] = pkbf(av[0], av[1]); A.w[1] = pkbf(av[2], av[3]);
    A.w[2] = pkbf(av[4], av[5]); A.w[3] = pkbf(av[6], av[7]);
    #pragma unroll
    for (int q = 0; q < 4; q++){
      const float* wr = Wl + (size_t)(q*16 + (l & 15))*256 + c;
      float4 u0 = *(const float4*)(wr);
      float4 u1 = *(const float4*)(wr + 4);
      union{u32 w[4]; short8 v;} Bv;
      Bv.w[0] = pkbf(u0.x, u0.y); Bv.w[1] = pkbf(u0.z, u0.w);
      Bv.w[2] = pkbf(u1.x, u1.y); Bv.w[3] = pkbf(u1.z, u1.w);
      acc[q] = __builtin_amdgcn_mfma_f32_16x16x32_bf16(A.v, Bv.v, acc[q], 0, 0, 0);
    }
  }
  int rb = rt*32 + w*16 + (l >> 4)*4;
  #pragma unroll
  for (int q = 0; q < 4; q++){
    int o = q*16 + (l & 15);
    float bv = bl[o];
    #pragma unroll
    for (int r = 0; r < 4; r++){
      float v = acc[q][r] + bv;
      out[(size_t)(rb + r)*64 + o] = fmaxf(v, 0.2f*v);
    }
  }
}

extern "C" void kernel_launch(void* const* d_in, const int* in_sizes, int n_in,
                              void* d_out, int out_size, void* d_ws, size_t ws_size,
                              hipStream_t stream) {
  const float* x  = (const float*)d_in[0];
  const int* adj  = (const int*)d_in[1];
  const float* W  = (const float*)d_in[2];
  const float* a1 = (const float*)d_in[3];
  const float* a2 = (const float*)d_in[4];
  const float* Wl = (const float*)d_in[5];
  const float* bl = (const float*)d_in[6];
  float* out = (float*)d_out;
  char* ws = (char*)d_ws;

  u32* adjw    = (u32*)(ws + 0x0000000);
  u16* hT      = (u16*)(ws + 0x0080000);
  u16* part    = (u16*)(ws + 0x0480000);
  float* Aarr  = (float*)(ws + 0x1480000);
  float* Barr  = (float*)(ws + 0x14A0000);
  float* Cexp  = (float*)(ws + 0x14C0000);
  float* Dexp  = (float*)(ws + 0x14E0000);
  float* Dsum  = (float*)(ws + 0x1500000);

  k_front<<<2688, 256, 0, stream>>>(x, W, a1, a2, adj, (u8*)adjw, hT, Aarr, Barr, Cexp, Dexp, Dsum);
  k_colsum<<<dim3(32, 16), 256, 0, stream>>>(adjw, Aarr, Barr, Cexp, Dexp, Dsum);
  k_pv<<<512, 256, 0, stream>>>(adjw, hT, Aarr, Barr, Cexp, Dexp, Dsum, part);
  k_out<<<256, 128, 0, stream>>>(part, Wl, bl, out);
}